// Round 3
// baseline (1786.875 us; speedup 1.0000x reference)
//
#include <hip/hip_runtime.h>
#include <hip/hip_bf16.h>
#include <cstdint>

#define B_   32
#define LQ_  2048
#define LK_  2048
#define D_   256
#define INV_T 0.0625f   // 1/16

typedef __attribute__((ext_vector_type(8))) short bf16x8;
typedef __attribute__((ext_vector_type(4))) float f32x4;

// fp32 -> bf16 RNE via the native cast: numerically identical to the manual
// bit-trick (both round-to-nearest-even), but the compiler can fuse adjacent
// pairs into v_cvt_pk_bf16_f32 (1 instr per 2 converts vs ~3-4 each).
__device__ __forceinline__ unsigned short f2bf(float f) {
    __hip_bfloat16 h = __float2bfloat16(f);
    unsigned short u;
    __builtin_memcpy(&u, &h, 2);
    return u;
}

// pack 4 bf16 into one 8B word for a single ds_write_b64
__device__ __forceinline__ unsigned long long pack4bf(float a, float b, float c, float d) {
    unsigned int lo = (unsigned int)f2bf(a) | ((unsigned int)f2bf(b) << 16);
    unsigned int hi = (unsigned int)f2bf(c) | ((unsigned int)f2bf(d) << 16);
    return (unsigned long long)lo | ((unsigned long long)hi << 32);
}

// ---------------------------------------------------------------------------
// Kernel 1 v4: P = mel ? 0 : exp((Q K^T)/16)  (unnormalized), rowsum += P
// Changes vs v3:
//   - LDS-transpose epilogue: S-tile round-trips through LDS (union with the
//     staging buffers, 2 chunks of 64 rows, 16B-granule XOR swizzle -> 2-way
//     conflicts = free). Each thread then owns 32 CONTIGUOUS cols of one row:
//     mel reads become int4, attn writes become float4 (4x fewer VMEM instrs,
//     perfect coalescing), rowsum is a 2-lane shuffle + 1 atomic per row.
//   - native bf16 converts on the staging path.
//   - keeps v3's batch->XCD affinity decode.
// ---------------------------------------------------------------------------
struct QkSmem {
    union {
        struct {
            unsigned short A[128][72];   // q tile, bf16, pad to 72
            unsigned short Bv[128][72];  // k tile, bf16
        } st;
        float ep[64][128];               // epilogue chunk: 64 rows x 128 cols
    };
};

__global__ __launch_bounds__(256) void qk_exp_kernel(
    const float* __restrict__ q, const float* __restrict__ kmat,
    const int* __restrict__ mel, float* __restrict__ attn,
    float* __restrict__ rowsum)
{
    // id = 0..8191; HW assigns XCD = id % 8 (round-robin dispatch).
    const int id  = blockIdx.x;
    const int xcd = id & 7;
    const int idx = id >> 3;                 // 0..1023
    const int b   = xcd + 8 * (idx >> 8);    // 4 batches per XCD, sequential
    const int t   = idx & 255;               // 16x16 tiles within batch
    const int m0  = (t >> 4) * 128;
    const int n0  = (t & 15) * 128;

    __shared__ QkSmem sm;

    const int tid  = threadIdx.x;
    const int wave = tid >> 6, lane = tid & 63;
    const int wm   = wave >> 1, wn = wave & 1;
    const int quad = lane >> 4, l16 = lane & 15;

    f32x4 acc[4][4];
#pragma unroll
    for (int i = 0; i < 4; ++i)
#pragma unroll
        for (int j = 0; j < 4; ++j) acc[i][j] = (f32x4)(0.0f);

    const float* qb = q    + (size_t)b * LQ_ * D_;
    const float* kb = kmat + (size_t)b * LK_ * D_;

    const int sr = tid >> 4;         // 0..15
    const int sc = (tid & 15) * 4;   // 0..60

    for (int kt = 0; kt < 4; ++kt) {
        const int kbase = kt * 64;
#pragma unroll
        for (int p = 0; p < 8; ++p) {
            const int row = sr + p * 16;
            float4 va = *(const float4*)&qb[(size_t)(m0 + row) * D_ + kbase + sc];
            float4 vb = *(const float4*)&kb[(size_t)(n0 + row) * D_ + kbase + sc];
            *(unsigned long long*)&sm.st.A[row][sc]  = pack4bf(va.x, va.y, va.z, va.w);
            *(unsigned long long*)&sm.st.Bv[row][sc] = pack4bf(vb.x, vb.y, vb.z, vb.w);
        }
        __syncthreads();
#pragma unroll
        for (int ks = 0; ks < 2; ++ks) {
            bf16x8 af[4], bfr[4];
#pragma unroll
            for (int i = 0; i < 4; ++i)
                af[i] = *(const bf16x8*)&sm.st.A[wm*64 + i*16 + l16][ks*32 + quad*8];
#pragma unroll
            for (int j = 0; j < 4; ++j)
                bfr[j] = *(const bf16x8*)&sm.st.Bv[wn*64 + j*16 + l16][ks*32 + quad*8];
#pragma unroll
            for (int i = 0; i < 4; ++i)
#pragma unroll
                for (int j = 0; j < 4; ++j)
                    acc[i][j] = __builtin_amdgcn_mfma_f32_16x16x32_bf16(
                        af[i], bfr[j], acc[i][j], 0, 0, 0);
        }
        __syncthreads();
    }

    // --- LDS-transpose epilogue ---
    float*      attnB = attn + (size_t)b * LQ_ * LK_;
    const int*  melB  = mel  + (size_t)b * LQ_ * LK_;

    for (int c = 0; c < 2; ++c) {
        // waves with wm==c scatter their S values (pre-scaled by 1/T) into LDS
        if (wm == c) {
#pragma unroll
            for (int i = 0; i < 4; ++i) {
#pragma unroll
                for (int j = 0; j < 4; ++j) {
#pragma unroll
                    for (int r = 0; r < 4; ++r) {
                        const int row = i*16 + quad*4 + r;      // 0..63 (chunk-local)
                        const int col = wn*64 + j*16 + l16;     // 0..127
                        const int ch  = (col >> 2) ^ (row & 7); // 16B-granule swizzle
                        sm.ep[row][(ch << 2) | (col & 3)] = acc[i][j][r] * INV_T;
                    }
                }
            }
        }
        __syncthreads();

        // all threads: thread owns (row = tid>>2, 32 contiguous cols)
        {
            const int row  = tid >> 2;       // 0..63
            const int g    = tid & 3;        // col group
            const int grow = m0 + c*64 + row;
            const size_t gbase = (size_t)grow * LK_ + n0;
            float rsum = 0.0f;
#pragma unroll
            for (int c4 = 0; c4 < 8; ++c4) {
                const int col = g*32 + c4*4;
                const int ch  = (col >> 2) ^ (row & 7);
                f32x4 s4 = *(const f32x4*)&sm.ep[row][ch << 2];
                int4  mv = *(const int4*)&melB[gbase + col];
                float p0 = mv.x ? 0.0f : __expf(s4.x);
                float p1 = mv.y ? 0.0f : __expf(s4.y);
                float p2 = mv.z ? 0.0f : __expf(s4.z);
                float p3 = mv.w ? 0.0f : __expf(s4.w);
                float4 st; st.x = p0; st.y = p1; st.z = p2; st.w = p3;
                *(float4*)&attnB[gbase + col] = st;
                rsum += (p0 + p1) + (p2 + p3);
            }
            rsum += __shfl_xor(rsum, 1);
            rsum += __shfl_xor(rsum, 2);
            if (g == 0)
                atomicAdd(&rowsum[(size_t)b * LQ_ + grow], rsum);
        }
        __syncthreads();   // chunk reads done before next chunk's writes
    }
}

// ---------------------------------------------------------------------------
// Kernel 2 v3.1: a = src ? 0 : P/l; attn <- a (in place); O = a @ V
// Unchanged structure vs round-2 v3 (affinity + register prefetch + swizzled
// LDS); only the bf16 conversion helpers switched to native casts.
// ---------------------------------------------------------------------------

// swizzled 16B-aligned frag pointer: row*128B + (chunk ^ key(row))*16B
__device__ __forceinline__ const bf16x8* lds_frag(
    const unsigned short (*arr)[64], int row, int chunk) {
    const int key = (row ^ (row >> 3)) & 7;
    return (const bf16x8*)&arr[row][(chunk ^ key) << 3];
}

// swizzled element offset for an 8B (4-elem) store at element index `e`
__device__ __forceinline__ int swz8(int row, int e) {
    return (e & 7) | ((((e >> 3) ^ row ^ (row >> 3)) & 7) << 3);
}

__global__ __launch_bounds__(256) void pv_norm_kernel(
    const float* __restrict__ v, const int* __restrict__ src,
    const float* __restrict__ rowsum, float* __restrict__ attn,
    float* __restrict__ out)
{
    // id = 0..1023; XCD = id % 8; batch pinned to XCD b%8.
    const int id  = blockIdx.x;
    const int xcd = id & 7;
    const int idx = id >> 3;                 // 0..127
    const int b   = xcd + 8 * (idx >> 5);    // 4 batches per XCD
    const int m0  = (idx & 31) * 64;         // 32 q-strips per batch

    __shared__ unsigned short As[64][64];    // a tile, bf16 [m][k], swizzled
    __shared__ unsigned short Vt[256][64];   // V^T tile, bf16 [n][k], swizzled

    const int tid  = threadIdx.x;
    const int wave = tid >> 6, lane = tid & 63;
    const int wn   = wave;                  // 4 waves cover D in 64-col strips
    const int quad = lane >> 4, l16 = lane & 15;

    f32x4 acc[4][4];
#pragma unroll
    for (int i = 0; i < 4; ++i)
#pragma unroll
        for (int j = 0; j < 4; ++j) acc[i][j] = (f32x4)(0.0f);

    const float* vb    = v    + (size_t)b * LK_ * D_;
    float*       attnB = attn + (size_t)b * LQ_ * LK_;
    const int*   srcB  = src  + (size_t)b * LQ_ * LK_;

    const int sr = tid >> 4;         // 0..15
    const int sc = (tid & 15) * 4;   // 0..60

    // per-thread reciprocal row sums for the 4 rows this thread normalizes
    float il[4];
#pragma unroll
    for (int p = 0; p < 4; ++p)
        il[p] = 1.0f / rowsum[(size_t)b * LQ_ + m0 + sr + p * 16];

    // --- prefetch tile kt=0 (attn + src) into registers ---
    float4 pv_r[4]; int4 sv_r[4];
#pragma unroll
    for (int p = 0; p < 4; ++p) {
        const int row = sr + p * 16;
        const size_t gi = (size_t)(m0 + row) * LK_ + sc;
        pv_r[p] = *(const float4*)&attnB[gi];
        sv_r[p] = *(const int4*)&srcB[gi];
    }

    for (int kt = 0; kt < 32; ++kt) {
        const int k0 = kt * 64;

        // Stage a-tile (64x64) from prefetched regs: normalize, mask,
        // write back fp32, packed bf16 ds_write_b64 (row-permuted swizzle,
        // conflict-free).
#pragma unroll
        for (int p = 0; p < 4; ++p) {
            const int row = sr + p * 16;
            const size_t gi = (size_t)(m0 + row) * LK_ + k0 + sc;
            const float ilp = il[p];
            float a0 = sv_r[p].x ? 0.0f : pv_r[p].x * ilp;
            float a1 = sv_r[p].y ? 0.0f : pv_r[p].y * ilp;
            float a2 = sv_r[p].z ? 0.0f : pv_r[p].z * ilp;
            float a3 = sv_r[p].w ? 0.0f : pv_r[p].w * ilp;
            float4 st; st.x = a0; st.y = a1; st.z = a2; st.w = a3;
            *(float4*)&attnB[gi] = st;
            *(unsigned long long*)&As[row][swz8(row, sc)] = pack4bf(a0, a1, a2, a3);
        }

        // Stage V^T tile (64 k-rows x 256 d-cols) via 4x4 register transpose.
        // With batch->XCD affinity these reads are L2-hot after first touch.
#pragma unroll
        for (int p = 0; p < 4; ++p) {
            const int bi  = tid + p * 256;
            const int bkv = (bi >> 6) * 4;   // 0..60 (wave-uniform)
            const int bn  = (bi & 63) * 4;   // 0..252
            const float* s0 = &vb[(size_t)(k0 + bkv) * D_ + bn];
            float4 r0 = *(const float4*)(s0);
            float4 r1 = *(const float4*)(s0 + D_);
            float4 r2 = *(const float4*)(s0 + 2 * D_);
            float4 r3 = *(const float4*)(s0 + 3 * D_);
            *(unsigned long long*)&Vt[bn+0][swz8(bn+0, bkv)] = pack4bf(r0.x, r1.x, r2.x, r3.x);
            *(unsigned long long*)&Vt[bn+1][swz8(bn+1, bkv)] = pack4bf(r0.y, r1.y, r2.y, r3.y);
            *(unsigned long long*)&Vt[bn+2][swz8(bn+2, bkv)] = pack4bf(r0.z, r1.z, r2.z, r3.z);
            *(unsigned long long*)&Vt[bn+3][swz8(bn+3, bkv)] = pack4bf(r0.w, r1.w, r2.w, r3.w);
        }

        // Prefetch next tile's attn/src (HBM-latency loads) BEFORE the
        // barrier so they overlap MFMA + both barriers + next a-stage.
        if (kt < 31) {
#pragma unroll
            for (int p = 0; p < 4; ++p) {
                const int row = sr + p * 16;
                const size_t gi = (size_t)(m0 + row) * LK_ + (k0 + 64) + sc;
                pv_r[p] = *(const float4*)&attnB[gi];
                sv_r[p] = *(const int4*)&srcB[gi];
            }
        }
        __syncthreads();

#pragma unroll
        for (int ks = 0; ks < 2; ++ks) {
            bf16x8 af[4], bfr[4];
            const int chunk = ks * 4 + quad;
#pragma unroll
            for (int i = 0; i < 4; ++i)
                af[i] = *lds_frag(As, i*16 + l16, chunk);
#pragma unroll
            for (int j = 0; j < 4; ++j)
                bfr[j] = *lds_frag(Vt, wn*64 + j*16 + l16, chunk);
#pragma unroll
            for (int i = 0; i < 4; ++i)
#pragma unroll
                for (int j = 0; j < 4; ++j)
                    acc[i][j] = __builtin_amdgcn_mfma_f32_16x16x32_bf16(
                        af[i], bfr[j], acc[i][j], 0, 0, 0);
        }
        __syncthreads();
    }

    // Epilogue: O tile 64 x 256
    float* outB = out + (size_t)b * LQ_ * D_;
#pragma unroll
    for (int i = 0; i < 4; ++i) {
#pragma unroll
        for (int j = 0; j < 4; ++j) {
#pragma unroll
            for (int r = 0; r < 4; ++r) {
                const int row = i*16 + quad*4 + r;
                const int col = wn*64 + j*16 + l16;
                outB[(size_t)(m0 + row) * D_ + col] = acc[i][j][r];
            }
        }
    }
}

extern "C" void kernel_launch(void* const* d_in, const int* in_sizes, int n_in,
                              void* d_out, int out_size, void* d_ws, size_t ws_size,
                              hipStream_t stream) {
    const float* q        = (const float*)d_in[0];
    const float* k        = (const float*)d_in[1];
    const float* v        = (const float*)d_in[2];
    const int*   src_mask = (const int*)d_in[3];
    const int*   mel_mask = (const int*)d_in[4];

    float* out  = (float*)d_out;                       // [B, LQ, D]
    float* attn = out + (size_t)B_ * LQ_ * D_;         // [B, LQ, LK]
    float* rowsum = (float*)d_ws;                      // [B, LQ]

    hipMemsetAsync(rowsum, 0, (size_t)B_ * LQ_ * sizeof(float), stream);

    qk_exp_kernel<<<dim3(16 * 16 * B_), 256, 0, stream>>>(
        q, k, mel_mask, attn, rowsum);

    pv_norm_kernel<<<dim3((LQ_ / 64) * B_), 256, 0, stream>>>(
        v, src_mask, rowsum, attn, out);
}